// Round 3
// baseline (7190.178 us; speedup 1.0000x reference)
//
#include <hip/hip_runtime.h>

typedef __bf16 bf16_t;
typedef __bf16 bf16x8 __attribute__((ext_vector_type(8)));
typedef float f32x4 __attribute__((ext_vector_type(4)));

#define B_ 64
#define T_ 256
#define F_ 1024
#define H_ 1024
#define G4_ 4096
#define NBLK_ 192
#define LPAD_ 1032   // row stride (elems): 2064B = 16B-aligned, worst 2-way LDS conflict (free)

#define MFMA16 __builtin_amdgcn_mfma_f32_16x16x32_bf16

__device__ __forceinline__ float sig_fast(float x) { return 1.f / (1.f + __expf(-x)); }
__device__ __forceinline__ float tanh_fast(float x) {
    float e = __expf(2.f * x);
    return 1.f - 2.f / (e + 1.f);
}
__device__ __forceinline__ float waveReduceSum(float v) {
    #pragma unroll
    for (int off = 32; off > 0; off >>= 1) v += __shfl_xor(v, off);
    return v;
}

// ---- custom device-scope grid barrier (no HIP cooperative machinery) ----
// On timeout: sets *flag (surfaced as +1000 in the final output) instead of hanging.
__device__ __forceinline__ void grid_barrier(unsigned* cnt, unsigned* gen, unsigned g,
                                             unsigned* flag) {
    __syncthreads();
    if (threadIdx.x == 0) {
        __threadfence();  // release: L2 writeback so other XCDs see this block's h stores
        unsigned a = __hip_atomic_fetch_add(cnt, 1u, __ATOMIC_ACQ_REL, __HIP_MEMORY_SCOPE_AGENT);
        if (a == NBLK_ - 1u) {
            __hip_atomic_store(cnt, 0u, __ATOMIC_RELAXED, __HIP_MEMORY_SCOPE_AGENT);
            __hip_atomic_store(gen, g + 1u, __ATOMIC_RELEASE, __HIP_MEMORY_SCOPE_AGENT);
        } else {
            int spins = 0;
            while (__hip_atomic_load(gen, __ATOMIC_ACQUIRE, __HIP_MEMORY_SCOPE_AGENT) < g + 1u) {
                __builtin_amdgcn_s_sleep(4);
                if (++spins > 800000) {  // ~80 ms: diagnostic escape, never a hang
                    __hip_atomic_fetch_or(flag, 1u, __ATOMIC_RELAXED, __HIP_MEMORY_SCOPE_AGENT);
                    break;
                }
            }
        }
        __threadfence();  // acquire: invalidate caches before reading other blocks' h
    }
    __syncthreads();
}

// ---------------- small prep kernels ----------------

__global__ void cast_kernel(const float* __restrict__ src, bf16_t* __restrict__ dst, int n) {
    int i = blockIdx.x * 256 + threadIdx.x;
    if (i < n) dst[i] = (bf16_t)src[i];
}

__global__ void bias_sum_kernel(const float* __restrict__ a, const float* __restrict__ b,
                                float* __restrict__ dst, int n) {
    int i = blockIdx.x * 256 + threadIdx.x;
    if (i < n) dst[i] = a[i] + b[i];
}

// w1 [1024,64] -> w1T bf16 [64,1024]
__global__ void w1t_kernel(const float* __restrict__ w1, bf16_t* __restrict__ w1T) {
    int i = blockIdx.x * 256 + threadIdx.x;  // 65536
    int j = i >> 10, u = i & 1023;
    w1T[i] = (bf16_t)w1[u * 64 + j];
}

// cov_temp[b,t] = (b%32==31)?0 : max(0, (sum_f x^2 - (sum_f x)^2/F)/T)
__global__ __launch_bounds__(256) void cov1_kernel(const float* __restrict__ x, float* __restrict__ ct) {
    int row = blockIdx.x * 4 + (threadIdx.x >> 6);  // b*T+t
    int lane = threadIdx.x & 63;
    const float* xr = x + (size_t)row * F_;
    float s1 = 0.f, s2 = 0.f;
    for (int f = lane; f < F_; f += 64) { float v = xr[f]; s1 += v; s2 += v * v; }
    s1 = waveReduceSum(s1);
    s2 = waveReduceSum(s2);
    if (lane == 0) {
        int b = row >> 8;
        float c = (s2 - s1 * s1 * (1.f / F_)) * (1.f / T_);
        ct[row] = ((b & 31) == 31) ? 0.f : fmaxf(c, 0.f);
    }
}

// cov_chan[b,f] (bf16) = (b%32==31)?0 : max(0, (sum_t x^2 - (sum_t x)^2/T)/F)
__global__ __launch_bounds__(256) void cov2_kernel(const float* __restrict__ x,
                                                   bf16_t* __restrict__ ccb) {
    int b = blockIdx.x;
    #pragma unroll
    for (int j = 0; j < 4; ++j) {
        int f = threadIdx.x + j * 256;
        float s1 = 0.f, s2 = 0.f;
        for (int t = 0; t < T_; ++t) {
            float v = x[((size_t)b * T_ + t) * F_ + f];
            s1 += v; s2 += v * v;
        }
        float c = (s2 - s1 * s1 * (1.f / T_)) * (1.f / F_);
        if ((b & 31) == 31) c = 0.f;
        ccb[b * F_ + f] = (bf16_t)fmaxf(c, 0.f);
    }
}

// ---------------- generic MFMA GEMM: C[M,N] = A[M,K] * B[N,K]^T (+bias) ----------------
__global__ __launch_bounds__(256) void gemm_bt_kernel(
    const bf16_t* __restrict__ A, const bf16_t* __restrict__ B,
    const float* __restrict__ bias, float* __restrict__ C,
    int M, int N, int K)
{
    const int wave = threadIdx.x >> 6;
    const int lane = threadIdx.x & 63;
    const int ln15 = lane & 15;
    const int quad = lane >> 4;
    const int n_base = blockIdx.x * 64;
    const int m_wave = blockIdx.y * 128 + wave * 32;

    f32x4 acc[2][4] = {};

    int rowA0 = m_wave + ln15;       if (rowA0 >= M) rowA0 = M - 1;
    int rowA1 = m_wave + 16 + ln15;  if (rowA1 >= M) rowA1 = M - 1;
    const bf16_t* Arow0 = A + (size_t)rowA0 * K + quad * 8;
    const bf16_t* Arow1 = A + (size_t)rowA1 * K + quad * 8;
    const bf16_t* Brow0 = B + (size_t)(n_base + 0 * 16 + ln15) * K + quad * 8;
    const bf16_t* Brow1 = B + (size_t)(n_base + 1 * 16 + ln15) * K + quad * 8;
    const bf16_t* Brow2 = B + (size_t)(n_base + 2 * 16 + ln15) * K + quad * 8;
    const bf16_t* Brow3 = B + (size_t)(n_base + 3 * 16 + ln15) * K + quad * 8;

    for (int k0 = 0; k0 < K; k0 += 32) {
        bf16x8 a0 = *(const bf16x8*)(Arow0 + k0);
        bf16x8 a1 = *(const bf16x8*)(Arow1 + k0);
        bf16x8 b0 = *(const bf16x8*)(Brow0 + k0);
        bf16x8 b1 = *(const bf16x8*)(Brow1 + k0);
        bf16x8 b2 = *(const bf16x8*)(Brow2 + k0);
        bf16x8 b3 = *(const bf16x8*)(Brow3 + k0);
        acc[0][0] = MFMA16(a0, b0, acc[0][0], 0, 0, 0);
        acc[0][1] = MFMA16(a0, b1, acc[0][1], 0, 0, 0);
        acc[0][2] = MFMA16(a0, b2, acc[0][2], 0, 0, 0);
        acc[0][3] = MFMA16(a0, b3, acc[0][3], 0, 0, 0);
        acc[1][0] = MFMA16(a1, b0, acc[1][0], 0, 0, 0);
        acc[1][1] = MFMA16(a1, b1, acc[1][1], 0, 0, 0);
        acc[1][2] = MFMA16(a1, b2, acc[1][2], 0, 0, 0);
        acc[1][3] = MFMA16(a1, b3, acc[1][3], 0, 0, 0);
    }

    #pragma unroll
    for (int s = 0; s < 2; ++s) {
        #pragma unroll
        for (int g = 0; g < 4; ++g) {
            int col = n_base + g * 16 + ln15;
            float bv = bias ? bias[col] : 0.f;
            #pragma unroll
            for (int r = 0; r < 4; ++r) {
                int row = m_wave + s * 16 + quad * 4 + r;
                if (row < M) C[(size_t)row * N + col] = acc[s][g][r] + bv;
            }
        }
    }
}

// ---------------- persistent dual-LSTM recurrence ----------------
// blocks 0..127:  LSTM1, 8 units each; LDS = Wih slice (rows 0..31) + Whh slice (rows 32..63)
//                 row n -> (gate n>>3, unit n&7); fused x-gemm + h-gemm.
// blocks 128..191: LSTM2, 16 units each; LDS = Whh2 slice (64 rows, row n -> gate n>>4, unit n&15);
//                 xg2 = ct[b,t]*v[b,col] + bias2 (rank-1).
__global__ __launch_bounds__(256, 1) void lstm_recur_kernel(
    const bf16_t* __restrict__ xb,    // [B,T,F] bf16
    const float*  __restrict__ ct,    // [B,T]
    const float*  __restrict__ v,     // [B,4096] fp32
    const float*  __restrict__ b1s,   // [4096]
    const float*  __restrict__ b2s,   // [4096]
    const float*  __restrict__ wih1,  // [4096,1024] fp32
    const float*  __restrict__ whh1,  // [4096,1024] fp32
    const float*  __restrict__ whh2,  // [4096,1024] fp32
    bf16_t* __restrict__ h1buf,       // [2][B][H] bf16
    bf16_t* __restrict__ h2buf,
    bf16_t* __restrict__ enc,         // [B,T,H] bf16
    float*  __restrict__ outl,        // [B,H] fp32
    unsigned* __restrict__ bar)
{
    __shared__ bf16_t wlds[64 * LPAD_];  // 132096 B

    const int blk  = blockIdx.x;
    const int is2  = (blk >= 128);
    const int wave = threadIdx.x >> 6;
    const int lane = threadIdx.x & 63;
    const int ln15 = lane & 15;
    const int quad = lane >> 4;
    const int bw   = wave * 16;

    unsigned* cnt  = bar;
    unsigned* gen  = bar + 64;   // 256 B apart
    unsigned* flag = bar + 96;   // timeout diagnostic

    int u0;
    if (!is2) {
        u0 = blk * 8;
        for (int i = threadIdx.x; i < 2 * 32 * 128; i += 256) {
            int mat = i >> 12;
            int rem = i & 4095;
            int n = rem >> 7;
            int kc = (rem & 127) * 8;
            int gate = n >> 3, unit = n & 7;
            const float* src = (mat ? whh1 : wih1) + (size_t)(gate * 1024 + u0 + unit) * H_ + kc;
            float4 f0 = *(const float4*)(src);
            float4 f1 = *(const float4*)(src + 4);
            bf16x8 w;
            w[0] = (bf16_t)f0.x; w[1] = (bf16_t)f0.y; w[2] = (bf16_t)f0.z; w[3] = (bf16_t)f0.w;
            w[4] = (bf16_t)f1.x; w[5] = (bf16_t)f1.y; w[6] = (bf16_t)f1.z; w[7] = (bf16_t)f1.w;
            *(bf16x8*)&wlds[(mat * 32 + n) * LPAD_ + kc] = w;
        }
        for (int i = threadIdx.x; i < 64 * 8; i += 256)
            h1buf[(size_t)(i >> 3) * H_ + u0 + (i & 7)] = (bf16_t)0.f;
    } else {
        u0 = (blk - 128) * 16;
        for (int i = threadIdx.x; i < 64 * 128; i += 256) {
            int n = i >> 7;
            int kc = (i & 127) * 8;
            int gate = n >> 4, unit = n & 15;
            const float* src = whh2 + (size_t)(gate * 1024 + u0 + unit) * H_ + kc;
            float4 f0 = *(const float4*)(src);
            float4 f1 = *(const float4*)(src + 4);
            bf16x8 w;
            w[0] = (bf16_t)f0.x; w[1] = (bf16_t)f0.y; w[2] = (bf16_t)f0.z; w[3] = (bf16_t)f0.w;
            w[4] = (bf16_t)f1.x; w[5] = (bf16_t)f1.y; w[6] = (bf16_t)f1.z; w[7] = (bf16_t)f1.w;
            *(bf16x8*)&wlds[n * LPAD_ + kc] = w;
        }
        for (int i = threadIdx.x; i < 64 * 16; i += 256)
            h2buf[(size_t)(i >> 4) * H_ + u0 + (i & 15)] = (bf16_t)0.f;
    }

    // per-thread constants
    float bias0 = 0.f, bias1 = 0.f;
    float vreg[4][4];
    float b2reg[4];
    if (!is2) {
        int col0 = (ln15 < 8) ? (u0 + ln15) : (1024 + u0 + ln15 - 8);
        int col1 = (ln15 < 8) ? (2048 + u0 + ln15) : (3072 + u0 + ln15 - 8);
        bias0 = b1s[col0];
        bias1 = b1s[col1];
    } else {
        #pragma unroll
        for (int g = 0; g < 4; ++g) {
            int colg = g * 1024 + u0 + ln15;
            b2reg[g] = b2s[colg];
            #pragma unroll
            for (int r = 0; r < 4; ++r)
                vreg[g][r] = v[(size_t)(bw + quad * 4 + r) * G4_ + colg];
        }
    }

    unsigned bg = 0;
    grid_barrier(cnt, gen, bg, flag); bg++;   // zeros + staging visible everywhere

    const bf16_t* hread  = is2 ? h2buf : h1buf;
    bf16_t*       hwrite = (is2 ? h2buf : h1buf) + B_ * H_;

    float c_st[4] = {0.f, 0.f, 0.f, 0.f};

    if (!is2) {
        for (int t = 0; t < T_; ++t) {
            f32x4 acc0 = {}, acc1 = {};
            const bf16_t* xA = xb + ((size_t)(bw + ln15) * T_ + t) * F_ + quad * 8;
            const bf16_t* hA = hread + (size_t)(bw + ln15) * H_ + quad * 8;
            const bf16_t* xB0 = &wlds[(0 + ln15) * LPAD_ + quad * 8];
            const bf16_t* xB1 = &wlds[(16 + ln15) * LPAD_ + quad * 8];
            const bf16_t* hB0 = &wlds[(32 + ln15) * LPAD_ + quad * 8];
            const bf16_t* hB1 = &wlds[(48 + ln15) * LPAD_ + quad * 8];
            for (int k0 = 0; k0 < H_; k0 += 32) {
                bf16x8 ax = *(const bf16x8*)(xA + k0);
                bf16x8 ah = *(const bf16x8*)(hA + k0);
                acc0 = MFMA16(ax, *(const bf16x8*)(xB0 + k0), acc0, 0, 0, 0);
                acc1 = MFMA16(ax, *(const bf16x8*)(xB1 + k0), acc1, 0, 0, 0);
                acc0 = MFMA16(ah, *(const bf16x8*)(hB0 + k0), acc0, 0, 0, 0);
                acc1 = MFMA16(ah, *(const bf16x8*)(hB1 + k0), acc1, 0, 0, 0);
            }
            #pragma unroll
            for (int r = 0; r < 4; ++r) {
                int b = bw + quad * 4 + r;
                float p0 = acc0[r] + bias0;          // i (ln15<8) or f (ln15>=8)
                float p1 = acc1[r] + bias1;          // g or o
                float q0 = __shfl_xor(p0, 8);
                float q1 = __shfl_xor(p1, 8);
                float ig = (ln15 < 8) ? p0 : q0;
                float fg = (ln15 < 8) ? q0 : p0;
                float gg = (ln15 < 8) ? p1 : q1;
                float og = (ln15 < 8) ? q1 : p1;
                ig = sig_fast(ig); fg = sig_fast(fg);
                gg = tanh_fast(gg); og = sig_fast(og);
                float c = fg * c_st[r] + ig * gg;
                c_st[r] = c;
                float h = og * tanh_fast(c);
                if (ln15 < 8) {
                    hwrite[(size_t)b * H_ + u0 + ln15] = (bf16_t)h;
                    if (t == T_ - 1) outl[(size_t)b * H_ + u0 + ln15] = h;
                }
            }
            grid_barrier(cnt, gen, bg, flag); bg++;
            bf16_t* tmp = (bf16_t*)hread; hread = hwrite; hwrite = tmp;
        }
    } else {
        for (int t = 0; t < T_; ++t) {
            f32x4 acc[4] = {};
            const bf16_t* hA = hread + (size_t)(bw + ln15) * H_ + quad * 8;
            const bf16_t* B0 = &wlds[(0 * 16 + ln15) * LPAD_ + quad * 8];
            const bf16_t* B1 = &wlds[(1 * 16 + ln15) * LPAD_ + quad * 8];
            const bf16_t* B2 = &wlds[(2 * 16 + ln15) * LPAD_ + quad * 8];
            const bf16_t* B3 = &wlds[(3 * 16 + ln15) * LPAD_ + quad * 8];
            for (int k0 = 0; k0 < H_; k0 += 32) {
                bf16x8 a = *(const bf16x8*)(hA + k0);
                acc[0] = MFMA16(a, *(const bf16x8*)(B0 + k0), acc[0], 0, 0, 0);
                acc[1] = MFMA16(a, *(const bf16x8*)(B1 + k0), acc[1], 0, 0, 0);
                acc[2] = MFMA16(a, *(const bf16x8*)(B2 + k0), acc[2], 0, 0, 0);
                acc[3] = MFMA16(a, *(const bf16x8*)(B3 + k0), acc[3], 0, 0, 0);
            }
            #pragma unroll
            for (int r = 0; r < 4; ++r) {
                int b = bw + quad * 4 + r;
                float cts = ct[b * T_ + t];
                float ig = sig_fast(acc[0][r] + cts * vreg[0][r] + b2reg[0]);
                float fg = sig_fast(acc[1][r] + cts * vreg[1][r] + b2reg[1]);
                float gg = tanh_fast(acc[2][r] + cts * vreg[2][r] + b2reg[2]);
                float og = sig_fast(acc[3][r] + cts * vreg[3][r] + b2reg[3]);
                float c = fg * c_st[r] + ig * gg;
                c_st[r] = c;
                float h = og * tanh_fast(c);
                hwrite[(size_t)b * H_ + u0 + ln15] = (bf16_t)h;
                enc[((size_t)b * T_ + t) * H_ + u0 + ln15] = (bf16_t)h;
            }
            grid_barrier(cnt, gen, bg, flag); bg++;
            bf16_t* tmp = (bf16_t*)hread; hread = hwrite; hwrite = tmp;
        }
    }
}

// ---------------- attention epilogue ----------------

__global__ __launch_bounds__(256) void p1_kernel(const bf16_t* __restrict__ enc,
                                                 float* __restrict__ Msm, float* __restrict__ Ssm) {
    int b = blockIdx.x;
    #pragma unroll
    for (int j = 0; j < 4; ++j) {
        int u = threadIdx.x + j * 256;
        const bf16_t* e = enc + (size_t)b * T_ * H_ + u;
        float m = -1e30f;
        for (int t = 0; t < T_; ++t) m = fmaxf(m, (float)e[(size_t)t * H_]);
        float s = 0.f;
        for (int t = 0; t < T_; ++t) s += __expf((float)e[(size_t)t * H_] - m);
        Msm[b * H_ + u] = m;
        Ssm[b * H_ + u] = s;
    }
}

__global__ __launch_bounds__(256) void p2_kernel(
    const bf16_t* __restrict__ enc, const float* __restrict__ Msm, const float* __restrict__ Ssm,
    const float* __restrict__ outl, const float* __restrict__ w_attn,
    bf16_t* __restrict__ saa, float* __restrict__ tapre) {
    int row = blockIdx.x;   // b*T+t
    int b = row >> 8;
    const bf16_t* erow = enc + (size_t)row * H_;
    float tsum = 0.f;
    for (int u = threadIdx.x; u < H_; u += 256) {
        float e = (float)erow[u];
        float sp = __expf(e - Msm[b * H_ + u]) / Ssm[b * H_ + u];
        saa[(size_t)row * H_ + u] = (bf16_t)(outl[b * H_ + u] * (sp + 1.f));
        tsum += tanh_fast(e) * w_attn[u];
    }
    tsum = waveReduceSum(tsum);
    __shared__ float red[4];
    if ((threadIdx.x & 63) == 0) red[threadIdx.x >> 6] = tsum;
    __syncthreads();
    if (threadIdx.x == 0) tapre[row] = red[0] + red[1] + red[2] + red[3];
}

// final: det = sigmoid(relu(r1)@w2 + b2); out = det*(1+sigmoid(tapre+b_attn))  [fp32 out!]
__global__ __launch_bounds__(256) void p4_kernel(
    const float* __restrict__ r1, const float* __restrict__ w2, const float* __restrict__ b2,
    const float* __restrict__ tapre, const float* __restrict__ b_attn,
    const unsigned* __restrict__ flag, float* __restrict__ out) {
    int row = blockIdx.x * 4 + (threadIdx.x >> 6);
    int lane = threadIdx.x & 63;
    float vsum = fmaxf(r1[(size_t)row * 64 + lane], 0.f) * w2[lane];
    vsum = waveReduceSum(vsum);
    if (lane == 0) {
        float det = sig_fast(vsum + b2[0]);
        float ta = sig_fast(tapre[row] + b_attn[0]);
        out[row] = det * (1.f + ta) + 1000.f * (float)(*flag);
    }
}

// ---------------- launcher ----------------

extern "C" void kernel_launch(void* const* d_in, const int* in_sizes, int n_in,
                              void* d_out, int out_size, void* d_ws, size_t ws_size,
                              hipStream_t stream) {
    const float* x      = (const float*)d_in[0];
    const float* W_ih1  = (const float*)d_in[1];
    const float* W_hh1  = (const float*)d_in[2];
    const float* b_ih1  = (const float*)d_in[3];
    const float* b_hh1  = (const float*)d_in[4];
    const float* W_ih2  = (const float*)d_in[5];
    const float* W_hh2  = (const float*)d_in[6];
    const float* b_ih2  = (const float*)d_in[7];
    const float* b_hh2  = (const float*)d_in[8];
    const float* w_attn = (const float*)d_in[9];
    const float* b_attn = (const float*)d_in[10];
    const float* w1     = (const float*)d_in[11];
    const float* b1     = (const float*)d_in[12];
    const float* w2     = (const float*)d_in[13];
    const float* b2     = (const float*)d_in[14];

    char* ws = (char*)d_ws;
    size_t off = 0;
    auto alloc = [&](size_t bytes) { size_t r = off; off = (off + bytes + 255) & ~(size_t)255; return r; };

    size_t o_bar  = alloc(512);
    size_t o_wih2 = alloc((size_t)G4_ * H_ * 2);      // 8 MB bf16 (for v-gemm)
    size_t o_xb   = alloc((size_t)B_ * T_ * F_ * 2);  // 32 MB
    size_t o_b1s  = alloc(G4_ * 4);
    size_t o_b2s  = alloc(G4_ * 4);
    size_t o_ct   = alloc(B_ * T_ * 4);
    size_t o_ccb  = alloc(B_ * F_ * 2);
    size_t o_v    = alloc((size_t)B_ * G4_ * 4);      // 1 MB
    size_t o_h1   = alloc(2 * B_ * H_ * 2);
    size_t o_h2   = alloc(2 * B_ * H_ * 2);
    size_t o_outl = alloc(B_ * H_ * 4);
    size_t o_w1t  = alloc(64 * H_ * 2);
    size_t o_msm  = alloc(B_ * H_ * 4);
    size_t o_ssm  = alloc(B_ * H_ * 4);
    size_t o_tap  = alloc(B_ * T_ * 4);
    size_t o_enc  = alloc((size_t)B_ * T_ * H_ * 2);  // 32 MB bf16
    size_t o_saa  = o_xb;                             // alias: xb dead after recurrence
    size_t o_r1   = o_enc;                            // alias: enc dead after p2

    if (ws_size < off) return;  // fail loudly as absmax mismatch, never a fault

    unsigned* bar  = (unsigned*)(ws + o_bar);
    bf16_t* wih2b  = (bf16_t*)(ws + o_wih2);
    bf16_t* xb     = (bf16_t*)(ws + o_xb);
    float*  b1s    = (float*)(ws + o_b1s);
    float*  b2s    = (float*)(ws + o_b2s);
    float*  ctp    = (float*)(ws + o_ct);
    bf16_t* ccb    = (bf16_t*)(ws + o_ccb);
    float*  vbuf   = (float*)(ws + o_v);
    bf16_t* h1     = (bf16_t*)(ws + o_h1);
    bf16_t* h2     = (bf16_t*)(ws + o_h2);
    float*  outl   = (float*)(ws + o_outl);
    bf16_t* w1t    = (bf16_t*)(ws + o_w1t);
    float*  msm    = (float*)(ws + o_msm);
    float*  ssm    = (float*)(ws + o_ssm);
    float*  tap    = (float*)(ws + o_tap);
    bf16_t* encp   = (bf16_t*)(ws + o_enc);
    bf16_t* saa    = (bf16_t*)(ws + o_saa);
    float*  r1     = (float*)(ws + o_r1);

    hipMemsetAsync(ws + o_bar, 0, 512, stream);

    int n = G4_ * H_;
    cast_kernel<<<(n + 255) / 256, 256, 0, stream>>>(W_ih2, wih2b, n);
    n = B_ * T_ * F_;
    cast_kernel<<<(n + 255) / 256, 256, 0, stream>>>(x, xb, n);
    bias_sum_kernel<<<16, 256, 0, stream>>>(b_ih1, b_hh1, b1s, G4_);
    bias_sum_kernel<<<16, 256, 0, stream>>>(b_ih2, b_hh2, b2s, G4_);
    cov1_kernel<<<B_ * T_ / 4, 256, 0, stream>>>(x, ctp);
    cov2_kernel<<<B_, 256, 0, stream>>>(x, ccb);
    w1t_kernel<<<256, 256, 0, stream>>>(w1, w1t);

    // v = cov_chan * Wih2^T (fp32 out)
    gemm_bt_kernel<<<dim3(G4_ / 64, 1), 256, 0, stream>>>(ccb, wih2b, nullptr, vbuf, B_, G4_, H_);

    lstm_recur_kernel<<<NBLK_, 256, 0, stream>>>(
        xb, ctp, vbuf, b1s, b2s, W_ih1, W_hh1, W_hh2, h1, h2, encp, outl, bar);

    p1_kernel<<<B_, 256, 0, stream>>>(encp, msm, ssm);
    p2_kernel<<<B_ * T_, 256, 0, stream>>>(encp, msm, ssm, outl, w_attn, saa, tap);
    // r1 = saa * w1T^T + b1 (fp32 out)
    gemm_bt_kernel<<<dim3(1, B_ * T_ / 128), 256, 0, stream>>>(saa, w1t, b1, r1, B_ * T_, 64, H_);
    p4_kernel<<<B_ * T_ / 4, 256, 0, stream>>>(r1, w2, b2, tap, b_attn, bar + 96, (float*)d_out);

    (void)in_sizes; (void)n_in; (void)out_size;
}

// Round 4
// 5535.033 us; speedup vs baseline: 1.2990x; 1.2990x over previous
//
#include <hip/hip_runtime.h>

typedef __bf16 bf16_t;
typedef __bf16 bf16x8 __attribute__((ext_vector_type(8)));
typedef float f32x4 __attribute__((ext_vector_type(4)));

#define B_ 64
#define T_ 256
#define F_ 1024
#define H_ 1024
#define G4_ 4096
#define NBLK_ 192
#define LPAD_ 1032   // row stride (elems): 2064B = 16B-aligned, worst 2-way LDS conflict (free)

#define MFMA16 __builtin_amdgcn_mfma_f32_16x16x32_bf16

__device__ __forceinline__ float sig_fast(float x) { return 1.f / (1.f + __expf(-x)); }
__device__ __forceinline__ float tanh_fast(float x) {
    float e = __expf(2.f * x);
    return 1.f - 2.f / (e + 1.f);
}
__device__ __forceinline__ float waveReduceSum(float v) {
    #pragma unroll
    for (int off = 32; off > 0; off >>= 1) v += __shfl_xor(v, off);
    return v;
}

// ---- all-to-all flag barrier (no contended RMW, relaxed polls) ----
// arr: group-base of packed per-block stamp words. idx: this block's index in group.
// n: group size (<=128). stamp: monotonically increasing (init 0 via memset).
// Release: thread0 __threadfence (wbL2) then write-through flag store.
// Acquire: relaxed polls (no per-poll inv!), then one __threadfence (invL2).
__device__ __forceinline__ void group_barrier(unsigned* arr, int idx, int n,
                                              unsigned stamp, unsigned* flag) {
    __syncthreads();
    if (threadIdx.x == 0) {
        __threadfence();  // release: flush this XCD's L2 so h stores reach LLC
        __hip_atomic_store(&arr[idx], stamp, __ATOMIC_RELAXED, __HIP_MEMORY_SCOPE_AGENT);
    }
    if (threadIdx.x < (unsigned)n) {
        int spins = 0;
        while (__hip_atomic_load(&arr[threadIdx.x], __ATOMIC_RELAXED,
                                 __HIP_MEMORY_SCOPE_AGENT) < stamp) {
            __builtin_amdgcn_s_sleep(1);
            if ((++spins & 1023) == 0) {
                if (__hip_atomic_load(flag, __ATOMIC_RELAXED, __HIP_MEMORY_SCOPE_AGENT)) break;
                if (spins > 2000000) {  // ~0.5 s: latch diagnostic, never hang
                    __hip_atomic_fetch_or(flag, 1u, __ATOMIC_RELAXED, __HIP_MEMORY_SCOPE_AGENT);
                    break;
                }
            }
        }
    }
    __syncthreads();
    if (threadIdx.x == 0) __threadfence();  // acquire: invalidate L1/L2 before reading remote h
    __syncthreads();
}

// ---------------- small prep kernels ----------------

__global__ void cast_kernel(const float* __restrict__ src, bf16_t* __restrict__ dst, int n) {
    int i = blockIdx.x * 256 + threadIdx.x;
    if (i < n) dst[i] = (bf16_t)src[i];
}

__global__ void bias_sum_kernel(const float* __restrict__ a, const float* __restrict__ b,
                                float* __restrict__ dst, int n) {
    int i = blockIdx.x * 256 + threadIdx.x;
    if (i < n) dst[i] = a[i] + b[i];
}

// w1 [1024,64] -> w1T bf16 [64,1024]
__global__ void w1t_kernel(const float* __restrict__ w1, bf16_t* __restrict__ w1T) {
    int i = blockIdx.x * 256 + threadIdx.x;  // 65536
    int j = i >> 10, u = i & 1023;
    w1T[i] = (bf16_t)w1[u * 64 + j];
}

// cov_temp[b,t] = (b%32==31)?0 : max(0, (sum_f x^2 - (sum_f x)^2/F)/T)
__global__ __launch_bounds__(256) void cov1_kernel(const float* __restrict__ x, float* __restrict__ ct) {
    int row = blockIdx.x * 4 + (threadIdx.x >> 6);  // b*T+t
    int lane = threadIdx.x & 63;
    const float* xr = x + (size_t)row * F_;
    float s1 = 0.f, s2 = 0.f;
    for (int f = lane; f < F_; f += 64) { float v = xr[f]; s1 += v; s2 += v * v; }
    s1 = waveReduceSum(s1);
    s2 = waveReduceSum(s2);
    if (lane == 0) {
        int b = row >> 8;
        float c = (s2 - s1 * s1 * (1.f / F_)) * (1.f / T_);
        ct[row] = ((b & 31) == 31) ? 0.f : fmaxf(c, 0.f);
    }
}

// cov_chan[b,f] (bf16) = (b%32==31)?0 : max(0, (sum_t x^2 - (sum_t x)^2/T)/F)
__global__ __launch_bounds__(256) void cov2_kernel(const float* __restrict__ x,
                                                   bf16_t* __restrict__ ccb) {
    int b = blockIdx.x;
    #pragma unroll
    for (int j = 0; j < 4; ++j) {
        int f = threadIdx.x + j * 256;
        float s1 = 0.f, s2 = 0.f;
        for (int t = 0; t < T_; ++t) {
            float v = x[((size_t)b * T_ + t) * F_ + f];
            s1 += v; s2 += v * v;
        }
        float c = (s2 - s1 * s1 * (1.f / T_)) * (1.f / F_);
        if ((b & 31) == 31) c = 0.f;
        ccb[b * F_ + f] = (bf16_t)fmaxf(c, 0.f);
    }
}

// ---------------- generic MFMA GEMM: C[M,N] = A[M,K] * B[N,K]^T (+bias) ----------------
__global__ __launch_bounds__(256) void gemm_bt_kernel(
    const bf16_t* __restrict__ A, const bf16_t* __restrict__ B,
    const float* __restrict__ bias, float* __restrict__ C,
    int M, int N, int K)
{
    const int wave = threadIdx.x >> 6;
    const int lane = threadIdx.x & 63;
    const int ln15 = lane & 15;
    const int quad = lane >> 4;
    const int n_base = blockIdx.x * 64;
    const int m_wave = blockIdx.y * 128 + wave * 32;

    f32x4 acc[2][4] = {};

    int rowA0 = m_wave + ln15;       if (rowA0 >= M) rowA0 = M - 1;
    int rowA1 = m_wave + 16 + ln15;  if (rowA1 >= M) rowA1 = M - 1;
    const bf16_t* Arow0 = A + (size_t)rowA0 * K + quad * 8;
    const bf16_t* Arow1 = A + (size_t)rowA1 * K + quad * 8;
    const bf16_t* Brow0 = B + (size_t)(n_base + 0 * 16 + ln15) * K + quad * 8;
    const bf16_t* Brow1 = B + (size_t)(n_base + 1 * 16 + ln15) * K + quad * 8;
    const bf16_t* Brow2 = B + (size_t)(n_base + 2 * 16 + ln15) * K + quad * 8;
    const bf16_t* Brow3 = B + (size_t)(n_base + 3 * 16 + ln15) * K + quad * 8;

    for (int k0 = 0; k0 < K; k0 += 32) {
        bf16x8 a0 = *(const bf16x8*)(Arow0 + k0);
        bf16x8 a1 = *(const bf16x8*)(Arow1 + k0);
        bf16x8 b0 = *(const bf16x8*)(Brow0 + k0);
        bf16x8 b1 = *(const bf16x8*)(Brow1 + k0);
        bf16x8 b2 = *(const bf16x8*)(Brow2 + k0);
        bf16x8 b3 = *(const bf16x8*)(Brow3 + k0);
        acc[0][0] = MFMA16(a0, b0, acc[0][0], 0, 0, 0);
        acc[0][1] = MFMA16(a0, b1, acc[0][1], 0, 0, 0);
        acc[0][2] = MFMA16(a0, b2, acc[0][2], 0, 0, 0);
        acc[0][3] = MFMA16(a0, b3, acc[0][3], 0, 0, 0);
        acc[1][0] = MFMA16(a1, b0, acc[1][0], 0, 0, 0);
        acc[1][1] = MFMA16(a1, b1, acc[1][1], 0, 0, 0);
        acc[1][2] = MFMA16(a1, b2, acc[1][2], 0, 0, 0);
        acc[1][3] = MFMA16(a1, b3, acc[1][3], 0, 0, 0);
    }

    #pragma unroll
    for (int s = 0; s < 2; ++s) {
        #pragma unroll
        for (int g = 0; g < 4; ++g) {
            int col = n_base + g * 16 + ln15;
            float bv = bias ? bias[col] : 0.f;
            #pragma unroll
            for (int r = 0; r < 4; ++r) {
                int row = m_wave + s * 16 + quad * 4 + r;
                if (row < M) C[(size_t)row * N + col] = acc[s][g][r] + bv;
            }
        }
    }
}

// ---------------- persistent dual-LSTM recurrence ----------------
// blocks 0..127:  LSTM1, 8 units each; LDS = Wih slice (rows 0..31) + Whh slice (rows 32..63)
//                 row n -> (gate n>>3, unit n&7); fused x-gemm + h-gemm. Barrier group A (128 flags).
// blocks 128..191: LSTM2, 16 units each; LDS = Whh2 slice (64 rows, row n -> gate n>>4, unit n&15);
//                 xg2 = ct[b,t]*v[b,col] + bias2 (rank-1). Barrier group B (64 flags).
__global__ __launch_bounds__(256, 1) void lstm_recur_kernel(
    const bf16_t* __restrict__ xb,    // [B,T,F] bf16
    const float*  __restrict__ ct,    // [B,T]
    const float*  __restrict__ v,     // [B,4096] fp32
    const float*  __restrict__ b1s,   // [4096]
    const float*  __restrict__ b2s,   // [4096]
    const float*  __restrict__ wih1,  // [4096,1024] fp32
    const float*  __restrict__ whh1,  // [4096,1024] fp32
    const float*  __restrict__ whh2,  // [4096,1024] fp32
    bf16_t* __restrict__ h1buf,       // [2][B][H] bf16
    bf16_t* __restrict__ h2buf,
    bf16_t* __restrict__ enc,         // [B,T,H] bf16
    float*  __restrict__ outl,        // [B,H] fp32
    unsigned* __restrict__ bar)
{
    __shared__ bf16_t wlds[64 * LPAD_];  // 132096 B

    const int blk  = blockIdx.x;
    const int is2  = (blk >= 128);
    const int wave = threadIdx.x >> 6;
    const int lane = threadIdx.x & 63;
    const int ln15 = lane & 15;
    const int quad = lane >> 4;
    const int bw   = wave * 16;

    unsigned* arr  = is2 ? (bar + 128) : bar;   // packed per-block stamp words
    const int gidx = is2 ? (blk - 128) : blk;
    const int gn   = is2 ? 64 : 128;
    unsigned* flag = bar + 224;                 // timeout diagnostic

    int u0;
    if (!is2) {
        u0 = blk * 8;
        for (int i = threadIdx.x; i < 2 * 32 * 128; i += 256) {
            int mat = i >> 12;
            int rem = i & 4095;
            int n = rem >> 7;
            int kc = (rem & 127) * 8;
            int gate = n >> 3, unit = n & 7;
            const float* src = (mat ? whh1 : wih1) + (size_t)(gate * 1024 + u0 + unit) * H_ + kc;
            float4 f0 = *(const float4*)(src);
            float4 f1 = *(const float4*)(src + 4);
            bf16x8 w;
            w[0] = (bf16_t)f0.x; w[1] = (bf16_t)f0.y; w[2] = (bf16_t)f0.z; w[3] = (bf16_t)f0.w;
            w[4] = (bf16_t)f1.x; w[5] = (bf16_t)f1.y; w[6] = (bf16_t)f1.z; w[7] = (bf16_t)f1.w;
            *(bf16x8*)&wlds[(mat * 32 + n) * LPAD_ + kc] = w;
        }
        for (int i = threadIdx.x; i < 64 * 8; i += 256)
            h1buf[(size_t)(i >> 3) * H_ + u0 + (i & 7)] = (bf16_t)0.f;
    } else {
        u0 = (blk - 128) * 16;
        for (int i = threadIdx.x; i < 64 * 128; i += 256) {
            int n = i >> 7;
            int kc = (i & 127) * 8;
            int gate = n >> 4, unit = n & 15;
            const float* src = whh2 + (size_t)(gate * 1024 + u0 + unit) * H_ + kc;
            float4 f0 = *(const float4*)(src);
            float4 f1 = *(const float4*)(src + 4);
            bf16x8 w;
            w[0] = (bf16_t)f0.x; w[1] = (bf16_t)f0.y; w[2] = (bf16_t)f0.z; w[3] = (bf16_t)f0.w;
            w[4] = (bf16_t)f1.x; w[5] = (bf16_t)f1.y; w[6] = (bf16_t)f1.z; w[7] = (bf16_t)f1.w;
            *(bf16x8*)&wlds[n * LPAD_ + kc] = w;
        }
        for (int i = threadIdx.x; i < 64 * 16; i += 256)
            h2buf[(size_t)(i >> 4) * H_ + u0 + (i & 15)] = (bf16_t)0.f;
    }

    // per-thread constants
    float bias0 = 0.f, bias1 = 0.f;
    float vreg[4][4];
    float b2reg[4];
    if (!is2) {
        int col0 = (ln15 < 8) ? (u0 + ln15) : (1024 + u0 + ln15 - 8);
        int col1 = (ln15 < 8) ? (2048 + u0 + ln15) : (3072 + u0 + ln15 - 8);
        bias0 = b1s[col0];
        bias1 = b1s[col1];
    } else {
        #pragma unroll
        for (int g = 0; g < 4; ++g) {
            int colg = g * 1024 + u0 + ln15;
            b2reg[g] = b2s[colg];
            #pragma unroll
            for (int r = 0; r < 4; ++r)
                vreg[g][r] = v[(size_t)(bw + quad * 4 + r) * G4_ + colg];
        }
    }

    unsigned stamp = 1;
    group_barrier(arr, gidx, gn, stamp, flag); stamp++;  // zeros + staging visible

    const bf16_t* hread  = is2 ? h2buf : h1buf;
    bf16_t*       hwrite = (is2 ? h2buf : h1buf) + B_ * H_;

    float c_st[4] = {0.f, 0.f, 0.f, 0.f};

    if (!is2) {
        for (int t = 0; t < T_; ++t) {
            f32x4 acc0 = {}, acc1 = {};
            const bf16_t* xA = xb + ((size_t)(bw + ln15) * T_ + t) * F_ + quad * 8;
            const bf16_t* hA = hread + (size_t)(bw + ln15) * H_ + quad * 8;
            const bf16_t* xB0 = &wlds[(0 + ln15) * LPAD_ + quad * 8];
            const bf16_t* xB1 = &wlds[(16 + ln15) * LPAD_ + quad * 8];
            const bf16_t* hB0 = &wlds[(32 + ln15) * LPAD_ + quad * 8];
            const bf16_t* hB1 = &wlds[(48 + ln15) * LPAD_ + quad * 8];
            #pragma unroll 4
            for (int k0 = 0; k0 < H_; k0 += 32) {
                bf16x8 ax = *(const bf16x8*)(xA + k0);
                bf16x8 ah = *(const bf16x8*)(hA + k0);
                acc0 = MFMA16(ax, *(const bf16x8*)(xB0 + k0), acc0, 0, 0, 0);
                acc1 = MFMA16(ax, *(const bf16x8*)(xB1 + k0), acc1, 0, 0, 0);
                acc0 = MFMA16(ah, *(const bf16x8*)(hB0 + k0), acc0, 0, 0, 0);
                acc1 = MFMA16(ah, *(const bf16x8*)(hB1 + k0), acc1, 0, 0, 0);
            }
            #pragma unroll
            for (int r = 0; r < 4; ++r) {
                int b = bw + quad * 4 + r;
                float p0 = acc0[r] + bias0;          // i (ln15<8) or f (ln15>=8)
                float p1 = acc1[r] + bias1;          // g or o
                float q0 = __shfl_xor(p0, 8);
                float q1 = __shfl_xor(p1, 8);
                float ig = (ln15 < 8) ? p0 : q0;
                float fg = (ln15 < 8) ? q0 : p0;
                float gg = (ln15 < 8) ? p1 : q1;
                float og = (ln15 < 8) ? q1 : p1;
                ig = sig_fast(ig); fg = sig_fast(fg);
                gg = tanh_fast(gg); og = sig_fast(og);
                float c = fg * c_st[r] + ig * gg;
                c_st[r] = c;
                float h = og * tanh_fast(c);
                if (ln15 < 8) {
                    hwrite[(size_t)b * H_ + u0 + ln15] = (bf16_t)h;
                    if (t == T_ - 1) outl[(size_t)b * H_ + u0 + ln15] = h;
                }
            }
            group_barrier(arr, gidx, gn, stamp, flag); stamp++;
            bf16_t* tmp = (bf16_t*)hread; hread = hwrite; hwrite = tmp;
        }
    } else {
        for (int t = 0; t < T_; ++t) {
            f32x4 acc[4] = {};
            const bf16_t* hA = hread + (size_t)(bw + ln15) * H_ + quad * 8;
            const bf16_t* B0 = &wlds[(0 * 16 + ln15) * LPAD_ + quad * 8];
            const bf16_t* B1 = &wlds[(1 * 16 + ln15) * LPAD_ + quad * 8];
            const bf16_t* B2 = &wlds[(2 * 16 + ln15) * LPAD_ + quad * 8];
            const bf16_t* B3 = &wlds[(3 * 16 + ln15) * LPAD_ + quad * 8];
            #pragma unroll 4
            for (int k0 = 0; k0 < H_; k0 += 32) {
                bf16x8 a = *(const bf16x8*)(hA + k0);
                acc[0] = MFMA16(a, *(const bf16x8*)(B0 + k0), acc[0], 0, 0, 0);
                acc[1] = MFMA16(a, *(const bf16x8*)(B1 + k0), acc[1], 0, 0, 0);
                acc[2] = MFMA16(a, *(const bf16x8*)(B2 + k0), acc[2], 0, 0, 0);
                acc[3] = MFMA16(a, *(const bf16x8*)(B3 + k0), acc[3], 0, 0, 0);
            }
            #pragma unroll
            for (int r = 0; r < 4; ++r) {
                int b = bw + quad * 4 + r;
                float cts = ct[b * T_ + t];
                float ig = sig_fast(acc[0][r] + cts * vreg[0][r] + b2reg[0]);
                float fg = sig_fast(acc[1][r] + cts * vreg[1][r] + b2reg[1]);
                float gg = tanh_fast(acc[2][r] + cts * vreg[2][r] + b2reg[2]);
                float og = sig_fast(acc[3][r] + cts * vreg[3][r] + b2reg[3]);
                float c = fg * c_st[r] + ig * gg;
                c_st[r] = c;
                float h = og * tanh_fast(c);
                hwrite[(size_t)b * H_ + u0 + ln15] = (bf16_t)h;
                enc[((size_t)b * T_ + t) * H_ + u0 + ln15] = (bf16_t)h;
            }
            group_barrier(arr, gidx, gn, stamp, flag); stamp++;
            bf16_t* tmp = (bf16_t*)hread; hread = hwrite; hwrite = tmp;
        }
    }
}

// ---------------- attention epilogue ----------------

__global__ __launch_bounds__(256) void p1_kernel(const bf16_t* __restrict__ enc,
                                                 float* __restrict__ Msm, float* __restrict__ Ssm) {
    int b = blockIdx.x;
    #pragma unroll
    for (int j = 0; j < 4; ++j) {
        int u = threadIdx.x + j * 256;
        const bf16_t* e = enc + (size_t)b * T_ * H_ + u;
        float m = -1e30f;
        for (int t = 0; t < T_; ++t) m = fmaxf(m, (float)e[(size_t)t * H_]);
        float s = 0.f;
        for (int t = 0; t < T_; ++t) s += __expf((float)e[(size_t)t * H_] - m);
        Msm[b * H_ + u] = m;
        Ssm[b * H_ + u] = s;
    }
}

__global__ __launch_bounds__(256) void p2_kernel(
    const bf16_t* __restrict__ enc, const float* __restrict__ Msm, const float* __restrict__ Ssm,
    const float* __restrict__ outl, const float* __restrict__ w_attn,
    bf16_t* __restrict__ saa, float* __restrict__ tapre) {
    int row = blockIdx.x;   // b*T+t
    int b = row >> 8;
    const bf16_t* erow = enc + (size_t)row * H_;
    float tsum = 0.f;
    for (int u = threadIdx.x; u < H_; u += 256) {
        float e = (float)erow[u];
        float sp = __expf(e - Msm[b * H_ + u]) / Ssm[b * H_ + u];
        saa[(size_t)row * H_ + u] = (bf16_t)(outl[b * H_ + u] * (sp + 1.f));
        tsum += tanh_fast(e) * w_attn[u];
    }
    tsum = waveReduceSum(tsum);
    __shared__ float red[4];
    if ((threadIdx.x & 63) == 0) red[threadIdx.x >> 6] = tsum;
    __syncthreads();
    if (threadIdx.x == 0) tapre[row] = red[0] + red[1] + red[2] + red[3];
}

// final: det = sigmoid(relu(r1)@w2 + b2); out = det*(1+sigmoid(tapre+b_attn))  [fp32 out]
__global__ __launch_bounds__(256) void p4_kernel(
    const float* __restrict__ r1, const float* __restrict__ w2, const float* __restrict__ b2,
    const float* __restrict__ tapre, const float* __restrict__ b_attn,
    const unsigned* __restrict__ flag, float* __restrict__ out) {
    int row = blockIdx.x * 4 + (threadIdx.x >> 6);
    int lane = threadIdx.x & 63;
    float vsum = fmaxf(r1[(size_t)row * 64 + lane], 0.f) * w2[lane];
    vsum = waveReduceSum(vsum);
    if (lane == 0) {
        float det = sig_fast(vsum + b2[0]);
        float ta = sig_fast(tapre[row] + b_attn[0]);
        out[row] = det * (1.f + ta) + 1000.f * (float)(*flag);
    }
}

// ---------------- launcher ----------------

extern "C" void kernel_launch(void* const* d_in, const int* in_sizes, int n_in,
                              void* d_out, int out_size, void* d_ws, size_t ws_size,
                              hipStream_t stream) {
    const float* x      = (const float*)d_in[0];
    const float* W_ih1  = (const float*)d_in[1];
    const float* W_hh1  = (const float*)d_in[2];
    const float* b_ih1  = (const float*)d_in[3];
    const float* b_hh1  = (const float*)d_in[4];
    const float* W_ih2  = (const float*)d_in[5];
    const float* W_hh2  = (const float*)d_in[6];
    const float* b_ih2  = (const float*)d_in[7];
    const float* b_hh2  = (const float*)d_in[8];
    const float* w_attn = (const float*)d_in[9];
    const float* b_attn = (const float*)d_in[10];
    const float* w1     = (const float*)d_in[11];
    const float* b1     = (const float*)d_in[12];
    const float* w2     = (const float*)d_in[13];
    const float* b2     = (const float*)d_in[14];

    char* ws = (char*)d_ws;
    size_t off = 0;
    auto alloc = [&](size_t bytes) { size_t r = off; off = (off + bytes + 255) & ~(size_t)255; return r; };

    size_t o_bar  = alloc(1024);                      // 128+64 flags + diag flag
    size_t o_wih2 = alloc((size_t)G4_ * H_ * 2);      // 8 MB bf16 (for v-gemm)
    size_t o_xb   = alloc((size_t)B_ * T_ * F_ * 2);  // 32 MB
    size_t o_b1s  = alloc(G4_ * 4);
    size_t o_b2s  = alloc(G4_ * 4);
    size_t o_ct   = alloc(B_ * T_ * 4);
    size_t o_ccb  = alloc(B_ * F_ * 2);
    size_t o_v    = alloc((size_t)B_ * G4_ * 4);      // 1 MB
    size_t o_h1   = alloc(2 * B_ * H_ * 2);
    size_t o_h2   = alloc(2 * B_ * H_ * 2);
    size_t o_outl = alloc(B_ * H_ * 4);
    size_t o_w1t  = alloc(64 * H_ * 2);
    size_t o_msm  = alloc(B_ * H_ * 4);
    size_t o_ssm  = alloc(B_ * H_ * 4);
    size_t o_tap  = alloc(B_ * T_ * 4);
    size_t o_enc  = alloc((size_t)B_ * T_ * H_ * 2);  // 32 MB bf16
    size_t o_saa  = o_xb;                             // alias: xb dead after recurrence
    size_t o_r1   = o_enc;                            // alias: enc dead after p2

    if (ws_size < off) return;  // fail loudly as absmax mismatch, never a fault

    unsigned* bar  = (unsigned*)(ws + o_bar);
    bf16_t* wih2b  = (bf16_t*)(ws + o_wih2);
    bf16_t* xb     = (bf16_t*)(ws + o_xb);
    float*  b1s    = (float*)(ws + o_b1s);
    float*  b2s    = (float*)(ws + o_b2s);
    float*  ctp    = (float*)(ws + o_ct);
    bf16_t* ccb    = (bf16_t*)(ws + o_ccb);
    float*  vbuf   = (float*)(ws + o_v);
    bf16_t* h1     = (bf16_t*)(ws + o_h1);
    bf16_t* h2     = (bf16_t*)(ws + o_h2);
    float*  outl   = (float*)(ws + o_outl);
    bf16_t* w1t    = (bf16_t*)(ws + o_w1t);
    float*  msm    = (float*)(ws + o_msm);
    float*  ssm    = (float*)(ws + o_ssm);
    float*  tap    = (float*)(ws + o_tap);
    bf16_t* encp   = (bf16_t*)(ws + o_enc);
    bf16_t* saa    = (bf16_t*)(ws + o_saa);
    float*  r1     = (float*)(ws + o_r1);

    hipMemsetAsync(ws + o_bar, 0, 1024, stream);

    int n = G4_ * H_;
    cast_kernel<<<(n + 255) / 256, 256, 0, stream>>>(W_ih2, wih2b, n);
    n = B_ * T_ * F_;
    cast_kernel<<<(n + 255) / 256, 256, 0, stream>>>(x, xb, n);
    bias_sum_kernel<<<16, 256, 0, stream>>>(b_ih1, b_hh1, b1s, G4_);
    bias_sum_kernel<<<16, 256, 0, stream>>>(b_ih2, b_hh2, b2s, G4_);
    cov1_kernel<<<B_ * T_ / 4, 256, 0, stream>>>(x, ctp);
    cov2_kernel<<<B_, 256, 0, stream>>>(x, ccb);
    w1t_kernel<<<256, 256, 0, stream>>>(w1, w1t);

    // v = cov_chan * Wih2^T (fp32 out)
    gemm_bt_kernel<<<dim3(G4_ / 64, 1), 256, 0, stream>>>(ccb, wih2b, nullptr, vbuf, B_, G4_, H_);

    lstm_recur_kernel<<<NBLK_, 256, 0, stream>>>(
        xb, ctp, vbuf, b1s, b2s, W_ih1, W_hh1, W_hh2, h1, h2, encp, outl, bar);

    p1_kernel<<<B_, 256, 0, stream>>>(encp, msm, ssm);
    p2_kernel<<<B_ * T_, 256, 0, stream>>>(encp, msm, ssm, outl, w_attn, saa, tap);
    // r1 = saa * w1T^T + b1 (fp32 out)
    gemm_bt_kernel<<<dim3(1, B_ * T_ / 128), 256, 0, stream>>>(saa, w1t, b1, r1, B_ * T_, 64, H_);
    p4_kernel<<<B_ * T_ / 4, 256, 0, stream>>>(r1, w2, b2, tap, b_attn, bar + 224, (float*)d_out);

    (void)in_sizes; (void)n_in; (void)out_size;
}